// Round 5
// baseline (237.609 us; speedup 1.0000x reference)
//
#include <hip/hip_runtime.h>

// LinearTextEmbedding: out[o] = (|bits[o & 4095]| > 0.5) ? 1 : 0 for the whole
// 48x1024x1024 float32 output. Write-BW bound: 201.3 MB stores, 16 KB reads.
//
// History: R0 (1 store/thr, 49k blocks) / R1 (24 stores/thr, 2k blocks) /
// R3 (4 NT stores/thr, 12k blocks) all give residual-after-poison ~67-75 us.
// Ambiguity: either stores run at ~3 TB/s (T1), or they run at ~6.4 TB/s and
// the residual hides a separate ~31 us d_out poison fill (T2).
//
// R4 PROBE: also store the 201 MB image into d_ws -> doubles store traffic
// with an observable side effect. dur_us delta == 201MB / store_bandwidth.
//   T1 -> +~67 us (kernel ~134 us, enters rocprof top-5)
//   T2 -> +~31 us (kernel ~63 us, stays hidden)

typedef float v4f __attribute__((ext_vector_type(4)));

#define N4    12582912u          // 48*1024*1024/4 float4 elements
#define BLK4  1024u              // float4 elements per block (16 KB)
#define NBLK  (N4 / BLK4)        // 12288 blocks
#define OUT_BYTES (50331648ull * 4ull)

__device__ __forceinline__ v4f bin4(v4f b) {
    v4f v;
    v.x = (fabsf(b.x) > 0.5f) ? 1.0f : 0.0f;
    v.y = (fabsf(b.y) > 0.5f) ? 1.0f : 0.0f;
    v.z = (fabsf(b.z) > 0.5f) ? 1.0f : 0.0f;
    v.w = (fabsf(b.w) > 0.5f) ? 1.0f : 0.0f;
    return v;
}

template <bool PROBE_WS>
__global__ __launch_bounds__(256) void
LinearTextEmbedding_57604101374655_kernel(const v4f* __restrict__ bits4,
                                          v4f* __restrict__ out,
                                          v4f* __restrict__ ws) {
    unsigned tid  = threadIdx.x;
    unsigned base = blockIdx.x * BLK4 + tid;
    v4f v0 = bin4(bits4[tid]);
    v4f v1 = bin4(bits4[256u + tid]);
    v4f v2 = bin4(bits4[512u + tid]);
    v4f v3 = bin4(bits4[768u + tid]);
    out[base]        = v0;
    out[base + 256u] = v1;
    out[base + 512u] = v2;
    out[base + 768u] = v3;
    if (PROBE_WS) {
        ws[base]        = v0;
        ws[base + 256u] = v1;
        ws[base + 512u] = v2;
        ws[base + 768u] = v3;
    }
}

extern "C" void kernel_launch(void* const* d_in, const int* in_sizes, int n_in,
                              void* d_out, int out_size, void* d_ws, size_t ws_size,
                              hipStream_t stream) {
    const v4f* bits4 = (const v4f*)d_in[0];
    v4f* out = (v4f*)d_out;
    if (d_ws != nullptr && ws_size >= OUT_BYTES) {
        LinearTextEmbedding_57604101374655_kernel<true>
            <<<NBLK, 256, 0, stream>>>(bits4, out, (v4f*)d_ws);
    } else {
        LinearTextEmbedding_57604101374655_kernel<false>
            <<<NBLK, 256, 0, stream>>>(bits4, out, nullptr);
    }
}

// Round 6
// 197.422 us; speedup vs baseline: 1.2036x; 1.2036x over previous
//
#include <hip/hip_runtime.h>

// LinearTextEmbedding: out[o] = (|bits[o & 4095]| > 0.5) ? 1 : 0 for the whole
// 48x1024x1024 float32 output (channel stride & image size are multiples of 4096).
// Write-BW bound: 201.3 MB stores, 16 KB reads. Roofline ~32 us at 6.3 TB/s.
//
// R4 probe (double-store into d_ws) settled the ambiguity: marginal store BW
// ~4.9-6 TB/s (+40.8 us for +201.3 MB), kernel never enters rocprof top-5 ->
// the out-only kernel is ~31-40 us, at the write roofline. The remaining
// ~160 us of dur_us is the harness's 805 MB 0xAA poison fill (119-132 us,
// +-10% run-to-run) + graph replay overhead — not kernel-addressable.
//
// Final form: contiguous 16 KB per block, 4 nontemporal float4 stores/thread,
// bits (16 KB) L1-resident, loaded as 4 float4/thread.

typedef float v4f __attribute__((ext_vector_type(4)));

#define N4    12582912u          // 48*1024*1024/4 float4 elements
#define BLK4  1024u              // float4 elements per block (16 KB)
#define NBLK  (N4 / BLK4)        // 12288 blocks

__device__ __forceinline__ v4f bin4(v4f b) {
    v4f v;
    v.x = (fabsf(b.x) > 0.5f) ? 1.0f : 0.0f;
    v.y = (fabsf(b.y) > 0.5f) ? 1.0f : 0.0f;
    v.z = (fabsf(b.z) > 0.5f) ? 1.0f : 0.0f;
    v.w = (fabsf(b.w) > 0.5f) ? 1.0f : 0.0f;
    return v;
}

__global__ __launch_bounds__(256) void
LinearTextEmbedding_57604101374655_kernel(const v4f* __restrict__ bits4,
                                          v4f* __restrict__ out) {
    unsigned tid  = threadIdx.x;
    unsigned base = blockIdx.x * BLK4 + tid;
    // Block base is a multiple of 1024, so bits index for store slot
    // (i*256 + tid) is just i*256 + tid.
    v4f v0 = bin4(bits4[tid]);
    v4f v1 = bin4(bits4[256u + tid]);
    v4f v2 = bin4(bits4[512u + tid]);
    v4f v3 = bin4(bits4[768u + tid]);
    __builtin_nontemporal_store(v0, &out[base]);
    __builtin_nontemporal_store(v1, &out[base + 256u]);
    __builtin_nontemporal_store(v2, &out[base + 512u]);
    __builtin_nontemporal_store(v3, &out[base + 768u]);
}

extern "C" void kernel_launch(void* const* d_in, const int* in_sizes, int n_in,
                              void* d_out, int out_size, void* d_ws, size_t ws_size,
                              hipStream_t stream) {
    const v4f* bits4 = (const v4f*)d_in[0];
    v4f* out = (v4f*)d_out;
    LinearTextEmbedding_57604101374655_kernel<<<NBLK, 256, 0, stream>>>(bits4, out);
}